// Round 13
// baseline (69.504 us; speedup 1.0000x reference)
//
#include <hip/hip_runtime.h>

// ================= Kernel 1: conv1/conv22 + 2x2 maxpool -> kv partial; Gram partial; xsum ========
// grid = B*32 = 512 (block = (b, pooled-row r) = 128 contiguous px = rows 2r,2r+1), block = 256
__global__ __launch_bounds__(256) void k1(const float* __restrict__ x,
    const float* __restrict__ w1, const float* __restrict__ b1,
    const float* __restrict__ w22, const float* __restrict__ b22,
    float* __restrict__ kvpart, float* __restrict__ Gpart, float* __restrict__ xsumpart)
{
  __shared__ float xl[64][132];    // padded: row stride 132 (528B, 16B-aligned; bank stride 4)
  __shared__ float wlt[64][64];
  __shared__ float bl[64];
  __shared__ float phil[32][33];
  __shared__ float glt[32][33];
  int t = threadIdx.x, blk = blockIdx.x;
  int tile = blk & 31, b = blk >> 5;
  const float* xb = x + ((size_t)b << 18) + tile*128;

  for (int v = t; v < 2048; v += 256) {
    int ch = v >> 5, rem = v & 31;
    *(float4*)&xl[ch][rem*4] = *(const float4*)(xb + ch*4096 + rem*4);
  }
  for (int v = t; v < 1024; v += 256) {
    int half = v >> 9, vv = v & 511;
    int o = vv >> 4, cb = (vv & 15) * 4;
    const float* src = (half ? w22 : w1) + o*64 + cb;
    float4 u = *(const float4*)src;
    int oo = o + half*32;
    wlt[cb+0][oo] = u.x; wlt[cb+1][oo] = u.y; wlt[cb+2][oo] = u.z; wlt[cb+3][oo] = u.w;
  }
  if (t < 32) bl[t] = b1[t];
  else if (t < 64) bl[t] = b22[t-32];
  __syncthreads();

  // ---- conv + maxpool (proven body; px[0:64]=row 2r, px[64:128]=row 2r+1)
  {
    int p = t & 31, og = t >> 5;
    float acc0[4][4], acc1[4][4];
    #pragma unroll
    for (int k = 0; k < 4; k++)
      #pragma unroll
      for (int px = 0; px < 4; px++) { acc0[k][px] = 0.f; acc1[k][px] = 0.f; }
    #pragma unroll 4
    for (int c = 0; c < 64; c++) {
      float2 x0 = *(const float2*)&xl[c][2*p];
      float2 x1 = *(const float2*)&xl[c][64 + 2*p];
      float4 wa = *(const float4*)&wlt[c][og*4];
      float4 wb = *(const float4*)&wlt[c][32 + og*4];
      float xs[4]  = {x0.x, x0.y, x1.x, x1.y};
      float was[4] = {wa.x, wa.y, wa.z, wa.w};
      float wbs[4] = {wb.x, wb.y, wb.z, wb.w};
      #pragma unroll
      for (int k = 0; k < 4; k++)
        #pragma unroll
        for (int px = 0; px < 4; px++) {
          acc0[k][px] += was[k] * xs[px];
          acc1[k][px] += wbs[k] * xs[px];
        }
    }
    #pragma unroll
    for (int k = 0; k < 4; k++) {
      int o = og*4 + k;
      float m1 = fmaxf(fmaxf(acc0[k][0], acc0[k][1]), fmaxf(acc0[k][2], acc0[k][3])) + bl[o];
      float m2 = fmaxf(fmaxf(acc1[k][0], acc1[k][1]), fmaxf(acc1[k][2], acc1[k][3])) + bl[32+o];
      glt[p][o]  = m1;
      phil[o][p] = m2;
    }
  }
  __syncthreads();

  // ---- kv partial
  float* kvp = kvpart + (size_t)blk * 1024;
  for (int e = t; e < 1024; e += 256) {
    int i = e >> 5, j = e & 31;
    float s = 0.f;
    #pragma unroll
    for (int q = 0; q < 32; q++) s += phil[i][q] * glt[q][j];
    kvp[e] = s;
  }

  // ---- Gram partial: thread owns 4x4 (c1,c2); float4 over p; padded stride -> 2-way banks (free)
  {
    int c1 = (t >> 4) * 4, c2 = (t & 15) * 4;
    float ga[4][4];
    #pragma unroll
    for (int i = 0; i < 4; i++)
      #pragma unroll
      for (int j = 0; j < 4; j++) ga[i][j] = 0.f;
    for (int p4 = 0; p4 < 128; p4 += 4) {
      float4 xa0 = *(const float4*)&xl[c1+0][p4];
      float4 xa1 = *(const float4*)&xl[c1+1][p4];
      float4 xa2 = *(const float4*)&xl[c1+2][p4];
      float4 xa3 = *(const float4*)&xl[c1+3][p4];
      float4 xb0 = *(const float4*)&xl[c2+0][p4];
      float4 xb1 = *(const float4*)&xl[c2+1][p4];
      float4 xb2 = *(const float4*)&xl[c2+2][p4];
      float4 xb3 = *(const float4*)&xl[c2+3][p4];
      float4 A[4] = {xa0, xa1, xa2, xa3};
      float4 Bv[4] = {xb0, xb1, xb2, xb3};
      #pragma unroll
      for (int i = 0; i < 4; i++)
        #pragma unroll
        for (int j = 0; j < 4; j++)
          ga[i][j] += A[i].x*Bv[j].x + A[i].y*Bv[j].y + A[i].z*Bv[j].z + A[i].w*Bv[j].w;
    }
    float* gp = Gpart + (size_t)blk * 4096;
    #pragma unroll
    for (int i = 0; i < 4; i++) {
      float4 r; r.x = ga[i][0]; r.y = ga[i][1]; r.z = ga[i][2]; r.w = ga[i][3];
      *(float4*)(gp + (c1+i)*64 + c2) = r;
    }
  }

  // ---- xsum partial
  {
    int c = t >> 2, q = t & 3;
    float s = 0.f;
    #pragma unroll 8
    for (int pp = 0; pp < 32; pp++) s += xl[c][q*32 + pp];
    s += __shfl_down(s, 1);
    s += __shfl_down(s, 2);
    if (q == 0) xsumpart[(size_t)blk*64 + c] = s;
  }
}

// ================= Kernel 2: WIDE reduction of kv/G/xsum partials (1 output elem per thread) =====
// grid = 324 blocks x 256 = 82944 threads = 16384 kv + 65536 G + 1024 xsum outputs
__global__ __launch_bounds__(256) void k2red(const float* __restrict__ kvpart,
    const float* __restrict__ Gpart, const float* __restrict__ xsumpart,
    float* __restrict__ kvred, float* __restrict__ Gred, float* __restrict__ xsumred)
{
  int tid = blockIdx.x * 256 + threadIdx.x;
  if (tid < 16384) {
    int bb = tid >> 10, e = tid & 1023;
    const float* kp = kvpart + ((size_t)bb << 15) + e;
    float s = 0.f;
    #pragma unroll
    for (int r = 0; r < 32; r++) s += kp[r*1024];
    kvred[tid] = s * (1.f/1024.f);
  } else if (tid < 81920) {
    int idx = tid - 16384;
    int bb = idx >> 12, e = idx & 4095;
    const float* gp = Gpart + ((size_t)bb << 17) + e;
    float s = 0.f;
    #pragma unroll
    for (int r = 0; r < 32; r++) s += gp[r*4096];
    Gred[idx] = s;
  } else if (tid < 82944) {
    int idx = tid - 81920;
    int bb = idx >> 6, e = idx & 63;
    const float* xp = xsumpart + ((size_t)bb << 11) + e;
    float s = 0.f;
    #pragma unroll
    for (int r = 0; r < 32; r++) s += xp[r*64];
    xsumred[idx] = s;
  }
}

// ================= Kernel 3: W[b], bias[b]; analytic BN sums from reduced G/xsum ================
// grid = B = 16, block = 256
// S1[b,c] = w_c.xsum + P*bias ; S2[b,c] = w_c^T G w_c + 2*bias*(w_c.xsum) + P*bias^2 (P=4096)
__global__ __launch_bounds__(256) void k3w(const float* __restrict__ kvred,
    const float* __restrict__ Gred, const float* __restrict__ xsumred,
    const float* __restrict__ w3, const float* __restrict__ b3,
    const float* __restrict__ w21, const float* __restrict__ b21,
    float* __restrict__ Wt, float* __restrict__ biasv, float* __restrict__ statb)
{
  __shared__ float kvl[1024];
  __shared__ float Sl[4096];
  __shared__ float w3t[2048];
  __shared__ float w21l[2048];
  __shared__ float wlds[4096];     // W as [ch*64+c]
  __shared__ float xbl[64];
  __shared__ float b21l[32];
  __shared__ float qpl[256];
  __shared__ float mdl[64], bsl[64];
  int t = threadIdx.x, b = blockIdx.x;

  for (int e = t; e < 1024; e += 256) kvl[e] = kvred[b*1024 + e];
  for (int e = t; e < 4096; e += 256) Sl[e] = Gred[b*4096 + e];
  if (t < 64) xbl[t] = xsumred[b*64 + t];
  for (int e = t; e < 2048; e += 256) { int c = e >> 5, j = e & 31; w3t[j*64+c] = w3[e]; }
  for (int e = t; e < 2048; e += 256) { int i = e >> 6, ch = e & 63; w21l[i*64+ch] = w21[e]; }
  if (t < 32) b21l[t] = b21[t];
  __syncthreads();

  if (t < 64) {
    int c = t;
    float A[32];
    #pragma unroll
    for (int i = 0; i < 32; i++) {
      float s = 0.f;
      #pragma unroll
      for (int j = 0; j < 32; j++) s += w3t[j*64+c] * kvl[i*32+j];
      A[i] = s;
    }
    float bias = b3[c];
    #pragma unroll
    for (int i = 0; i < 32; i++) bias += A[i] * b21l[i];
    biasv[b*64 + c] = bias;
    float md = 0.f;
    #pragma unroll
    for (int ch = 0; ch < 64; ch++) {
      float wv = 0.f;
      #pragma unroll
      for (int i = 0; i < 32; i++) wv += A[i] * w21l[i*64+ch];
      wlds[ch*64 + c] = wv;
      md += wv * xbl[ch];
    }
    mdl[c] = md;
    bsl[c] = bias;
  }
  __syncthreads();

  for (int v = t; v < 1024; v += 256)
    *(float4*)(Wt + ((size_t)b << 12) + v*4) = *(const float4*)&wlds[v*4];

  {
    int c = t & 63, kg = t >> 6;
    float qp = 0.f;
    for (int k1i = kg*16; k1i < kg*16 + 16; k1i++) {
      float tmp = 0.f;
      #pragma unroll
      for (int k2i = 0; k2i < 64; k2i++) tmp += Sl[k1i*64 + k2i] * wlds[k2i*64 + c];
      qp += wlds[k1i*64 + c] * tmp;
    }
    qpl[kg*64 + c] = qp;
  }
  __syncthreads();
  if (t < 64) {
    int c = t;
    float q = qpl[c] + qpl[64+c] + qpl[128+c] + qpl[192+c];
    float bias = bsl[c], md = mdl[c];
    statb[b*128 + c]      = md + 4096.f*bias;
    statb[b*128 + 64 + c] = q + 2.f*bias*md + 4096.f*bias*bias;
  }
}

// ================= Kernel 4: scale/shift from statb; out GEMM; + x; store ========================
// grid = 512, block = 256
__global__ __launch_bounds__(256) void k4(const float* __restrict__ x,
    const float* __restrict__ Wt, const float* __restrict__ biasv,
    const float* __restrict__ statb,
    const float* __restrict__ gamma, const float* __restrict__ beta,
    float* __restrict__ out)
{
  __shared__ float xt[64][128];
  __shared__ float wl[64][64];
  __shared__ float scl[64], shl[64];
  int t = threadIdx.x, blk = blockIdx.x;
  int tile = blk & 31, b = blk >> 5;
  const float* xb = x + ((size_t)b << 18) + tile*128;
  for (int v = t; v < 2048; v += 256) {
    int ch = v >> 5, rem = v & 31;
    *(float4*)&xt[ch][rem*4] = *(const float4*)(xb + ch*4096 + rem*4);
  }
  const float* wb = Wt + ((size_t)b << 12);
  for (int v = t; v < 1024; v += 256)
    *(float4*)&wl[v >> 4][(v & 15)*4] = *(const float4*)(wb + v*4);
  if (t < 64) {
    float s1 = 0.f, s2 = 0.f;
    #pragma unroll
    for (int bb = 0; bb < 16; bb++) {
      s1 += statb[bb*128 + t];
      s2 += statb[bb*128 + 64 + t];
    }
    const float inv_cnt = 1.f / 65536.f;           // B*H*W
    float mu  = s1 * inv_cnt;
    float var = s2 * inv_cnt - mu*mu;
    float sc  = gamma[t] * rsqrtf(var + 1e-5f);
    scl[t] = sc;
    shl[t] = beta[t] - sc*mu;
  }
  __syncthreads();

  int pg = t & 15, cg = t >> 4;
  int p0 = pg*4, c0 = cg*4;
  float acc[4][8];
  #pragma unroll
  for (int ci = 0; ci < 4; ci++)
    #pragma unroll
    for (int pj = 0; pj < 8; pj++) acc[ci][pj] = 0.f;
  #pragma unroll 4
  for (int k = 0; k < 64; k++) {
    float4 w4 = *(const float4*)&wl[k][c0];
    float4 xa = *(const float4*)&xt[k][p0];
    float4 xc = *(const float4*)&xt[k][p0 + 64];
    float xs[8] = {xa.x, xa.y, xa.z, xa.w, xc.x, xc.y, xc.z, xc.w};
    float ws[4] = {w4.x, w4.y, w4.z, w4.w};
    #pragma unroll
    for (int ci = 0; ci < 4; ci++)
      #pragma unroll
      for (int pj = 0; pj < 8; pj++) acc[ci][pj] += ws[ci] * xs[pj];
  }
  float4 bias4 = *(const float4*)(biasv + b*64 + c0);
  float bb[4] = {bias4.x, bias4.y, bias4.z, bias4.w};
  float* ob = out + ((size_t)b << 18) + (size_t)tile*128;
  #pragma unroll
  for (int ci = 0; ci < 4; ci++) {
    int c = c0 + ci;
    float sc = scl[c], sh = shl[c];
    float4 xa = *(const float4*)&xt[c][p0];
    float4 xc = *(const float4*)&xt[c][p0 + 64];
    float4 ra, rb;
    ra.x = sc*(acc[ci][0]+bb[ci]) + sh + xa.x;
    ra.y = sc*(acc[ci][1]+bb[ci]) + sh + xa.y;
    ra.z = sc*(acc[ci][2]+bb[ci]) + sh + xa.z;
    ra.w = sc*(acc[ci][3]+bb[ci]) + sh + xa.w;
    rb.x = sc*(acc[ci][4]+bb[ci]) + sh + xc.x;
    rb.y = sc*(acc[ci][5]+bb[ci]) + sh + xc.y;
    rb.z = sc*(acc[ci][6]+bb[ci]) + sh + xc.z;
    rb.w = sc*(acc[ci][7]+bb[ci]) + sh + xc.w;
    *(float4*)(ob + (size_t)c*4096 + p0)      = ra;
    *(float4*)(ob + (size_t)c*4096 + p0 + 64) = rb;
  }
}

extern "C" void kernel_launch(void* const* d_in, const int* in_sizes, int n_in,
                              void* d_out, int out_size, void* d_ws, size_t ws_size,
                              hipStream_t stream)
{
  const float* x    = (const float*)d_in[0];
  const float* w1   = (const float*)d_in[1];
  const float* b1   = (const float*)d_in[2];
  const float* w21  = (const float*)d_in[3];
  const float* b21  = (const float*)d_in[4];
  const float* w22  = (const float*)d_in[5];
  const float* b22  = (const float*)d_in[6];
  const float* w3   = (const float*)d_in[7];
  const float* b3   = (const float*)d_in[8];
  const float* gamma= (const float*)d_in[9];
  const float* beta = (const float*)d_in[10];

  float* ws       = (float*)d_ws;
  float* kvpart   = ws;               // 524288
  float* Gpart    = ws + 524288;      // 2097152
  float* xsumpart = ws + 2621440;     // 32768
  float* kvred    = ws + 2654208;     // 16384
  float* Gred     = ws + 2670592;     // 65536
  float* xsumred  = ws + 2736128;     // 1024
  float* Wt       = ws + 2737152;     // 65536
  float* biasv    = ws + 2802688;     // 1024
  float* statb    = ws + 2803712;     // 2048

  hipLaunchKernelGGL(k1,    dim3(512), dim3(256), 0, stream,
                     x, w1, b1, w22, b22, kvpart, Gpart, xsumpart);
  hipLaunchKernelGGL(k2red, dim3(324), dim3(256), 0, stream,
                     kvpart, Gpart, xsumpart, kvred, Gred, xsumred);
  hipLaunchKernelGGL(k3w,   dim3(16),  dim3(256), 0, stream,
                     kvred, Gred, xsumred, w3, b3, w21, b21, Wt, biasv, statb);
  hipLaunchKernelGGL(k4,    dim3(512), dim3(256), 0, stream,
                     x, Wt, biasv, statb, gamma, beta, (float*)d_out);
}

// Round 14
// 61.782 us; speedup vs baseline: 1.1250x; 1.1250x over previous
//
#include <hip/hip_runtime.h>

// ================= Kernel A: conv1/conv22 + 2x2 maxpool -> per-block kv partial ==================
// grid = B*32 = 512 (one block per (b, pooled-row)), block = 256
__global__ __launch_bounds__(256) void kA(const float* __restrict__ x,
    const float* __restrict__ w1, const float* __restrict__ b1,
    const float* __restrict__ w22, const float* __restrict__ b22,
    float* __restrict__ kvpart)
{
  __shared__ float xl[64][128];
  __shared__ float wlt[64][64];
  __shared__ float bl[64];
  __shared__ float phil[32][33];
  __shared__ float glt[32][33];
  int t = threadIdx.x;
  int b = blockIdx.x >> 5, r = blockIdx.x & 31;
  const float* xb = x + ((size_t)b << 18);
  for (int v = t; v < 2048; v += 256) {
    int c = v >> 5, rem = v & 31;
    int h2 = rem >> 4, wv = rem & 15;
    float4 u = *(const float4*)(xb + c*4096 + (2*r + h2)*64 + wv*4);
    float* dst = &xl[c][h2*64 + wv*4];
    dst[0] = u.x; dst[1] = u.y; dst[2] = u.z; dst[3] = u.w;
  }
  for (int v = t; v < 1024; v += 256) {
    int half = v >> 9, vv = v & 511;
    int o = vv >> 4, cb = (vv & 15) * 4;
    const float* src = (half ? w22 : w1) + o*64 + cb;
    float4 u = *(const float4*)src;
    int oo = o + half*32;
    wlt[cb+0][oo] = u.x; wlt[cb+1][oo] = u.y; wlt[cb+2][oo] = u.z; wlt[cb+3][oo] = u.w;
  }
  if (t < 32) bl[t] = b1[t];
  else if (t < 64) bl[t] = b22[t-32];
  __syncthreads();

  int p = t & 31, og = t >> 5;
  float acc0[4][4], acc1[4][4];
  #pragma unroll
  for (int k = 0; k < 4; k++)
    #pragma unroll
    for (int px = 0; px < 4; px++) { acc0[k][px] = 0.f; acc1[k][px] = 0.f; }
  #pragma unroll 4
  for (int c = 0; c < 64; c++) {
    float2 x0 = *(const float2*)&xl[c][2*p];
    float2 x1 = *(const float2*)&xl[c][64 + 2*p];
    float4 wa = *(const float4*)&wlt[c][og*4];
    float4 wb = *(const float4*)&wlt[c][32 + og*4];
    float xs[4]  = {x0.x, x0.y, x1.x, x1.y};
    float was[4] = {wa.x, wa.y, wa.z, wa.w};
    float wbs[4] = {wb.x, wb.y, wb.z, wb.w};
    #pragma unroll
    for (int k = 0; k < 4; k++)
      #pragma unroll
      for (int px = 0; px < 4; px++) {
        acc0[k][px] += was[k] * xs[px];
        acc1[k][px] += wbs[k] * xs[px];
      }
  }
  #pragma unroll
  for (int k = 0; k < 4; k++) {
    int o = og*4 + k;
    float m1 = fmaxf(fmaxf(acc0[k][0], acc0[k][1]), fmaxf(acc0[k][2], acc0[k][3])) + bl[o];
    float m2 = fmaxf(fmaxf(acc1[k][0], acc1[k][1]), fmaxf(acc1[k][2], acc1[k][3])) + bl[32+o];
    glt[p][o]  = m1;
    phil[o][p] = m2;
  }
  __syncthreads();
  float* kvp = kvpart + (size_t)blockIdx.x * 1024;
  for (int e = t; e < 1024; e += 256) {
    int i = e >> 5, j = e & 31;
    float s = 0.f;
    #pragma unroll
    for (int q = 0; q < 32; q++) s += phil[i][q] * glt[q][j];
    kvp[e] = s;
  }
}

// ================= Kernel B: kv reduce (coalesced) + W[b] build + zero statb[b] ==================
// grid = B = 16, block = 256. Stores W transposed: Wt[b][k][c].
__global__ __launch_bounds__(256) void kB(const float* __restrict__ kvpart,
    const float* __restrict__ w3, const float* __restrict__ b3,
    const float* __restrict__ w21, const float* __restrict__ b21,
    float* __restrict__ Wt, float* __restrict__ biasv, float* __restrict__ statb)
{
  __shared__ float kvl[32][32];
  __shared__ float w3t[32][64];
  __shared__ float w21l[32][64];
  __shared__ float b21l[32];
  int t = threadIdx.x, b = blockIdx.x;
  if (t < 128) statb[b*128 + t] = 0.f;             // zero this batch's stat slot for kC's atomics
  for (int e = t; e < 1024; e += 256) {
    float s = 0.f;
    const float* kp = kvpart + ((size_t)b << 15) + e;
    #pragma unroll
    for (int r = 0; r < 32; r++) s += kp[r*1024];  // coalesced across threads for each r
    kvl[e>>5][e&31] = s * (1.f/1024.f);
  }
  for (int e = t; e < 2048; e += 256) { int c = e >> 5, j = e & 31; w3t[j][c] = w3[e]; }
  for (int e = t; e < 2048; e += 256) { int i = e >> 6, ch = e & 63; w21l[i][ch] = w21[e]; }
  if (t < 32) b21l[t] = b21[t];
  __syncthreads();
  if (t < 64) {
    int c = t;
    float A[32];
    #pragma unroll
    for (int i = 0; i < 32; i++) {
      float s = 0.f;
      #pragma unroll
      for (int j = 0; j < 32; j++) s += w3t[j][c] * kvl[i][j];
      A[i] = s;
    }
    float bias = b3[c];
    #pragma unroll
    for (int i = 0; i < 32; i++) bias += A[i] * b21l[i];
    biasv[b*64 + c] = bias;
    float* Wb = Wt + (size_t)b*4096;
    #pragma unroll
    for (int ch = 0; ch < 64; ch++) {
      float s = 0.f;
      #pragma unroll
      for (int i = 0; i < 32; i++) s += A[i] * w21l[i][ch];
      Wb[ch*64 + c] = s;                           // Wt[k=ch][c]
    }
  }
}

// ================= Kernel C: z = W[b]@x + bias; per-batch BN sums via light atomics ==============
// grid = B*32 = 512, block = 256.  pg = t&15 (px group), cg = t>>4 (4-channel group)
__global__ __launch_bounds__(256) void kC(const float* __restrict__ x,
    const float* __restrict__ Wt, const float* __restrict__ biasv,
    float* __restrict__ statb)
{
  __shared__ float xt[64][128];
  __shared__ float wl[64][64];
  __shared__ float lstat[128];
  int t = threadIdx.x, blk = blockIdx.x;
  int tile = blk & 31, b = blk >> 5;
  const float* xb = x + ((size_t)b << 18) + tile*128;
  for (int v = t; v < 2048; v += 256) {
    int ch = v >> 5, rem = v & 31;
    *(float4*)&xt[ch][rem*4] = *(const float4*)(xb + ch*4096 + rem*4);
  }
  const float* wb = Wt + ((size_t)b << 12);
  for (int v = t; v < 1024; v += 256)
    *(float4*)&wl[v >> 4][(v & 15)*4] = *(const float4*)(wb + v*4);
  if (t < 128) lstat[t] = 0.f;
  __syncthreads();

  int pg = t & 15, cg = t >> 4;
  int p0 = pg*4, c0 = cg*4;
  float acc[4][8];
  #pragma unroll
  for (int ci = 0; ci < 4; ci++)
    #pragma unroll
    for (int pj = 0; pj < 8; pj++) acc[ci][pj] = 0.f;
  #pragma unroll 4
  for (int k = 0; k < 64; k++) {
    float4 w4 = *(const float4*)&wl[k][c0];
    float4 xa = *(const float4*)&xt[k][p0];
    float4 xc = *(const float4*)&xt[k][p0 + 64];
    float xs[8] = {xa.x, xa.y, xa.z, xa.w, xc.x, xc.y, xc.z, xc.w};
    float ws[4] = {w4.x, w4.y, w4.z, w4.w};
    #pragma unroll
    for (int ci = 0; ci < 4; ci++)
      #pragma unroll
      for (int pj = 0; pj < 8; pj++) acc[ci][pj] += ws[ci] * xs[pj];
  }
  float4 bias4 = *(const float4*)(biasv + b*64 + c0);
  float bb[4] = {bias4.x, bias4.y, bias4.z, bias4.w};
  #pragma unroll
  for (int ci = 0; ci < 4; ci++) {
    float s1 = 0.f, s2 = 0.f;
    #pragma unroll
    for (int pj = 0; pj < 8; pj++) {
      float z = acc[ci][pj] + bb[ci];
      s1 += z; s2 += z*z;
    }
    #pragma unroll
    for (int off = 1; off < 16; off <<= 1) { s1 += __shfl_xor(s1, off); s2 += __shfl_xor(s2, off); }
    if (pg == 0) { atomicAdd(&lstat[c0+ci], s1); atomicAdd(&lstat[64+c0+ci], s2); }
  }
  __syncthreads();
  // per-batch accumulator: only 32 blocks contend per address
  if (t < 128) atomicAdd(&statb[b*128 + t], lstat[t]);
}

// ================= Kernel D: reduce statb (8 KB, L2-hot) -> scale/shift; out GEMM; store =========
// grid = 512, block = 256
__global__ __launch_bounds__(256) void kD(const float* __restrict__ x,
    const float* __restrict__ Wt, const float* __restrict__ biasv,
    const float* __restrict__ statb,
    const float* __restrict__ gamma, const float* __restrict__ beta,
    float* __restrict__ out)
{
  __shared__ float xt[64][128];
  __shared__ float wl[64][64];
  __shared__ float scl[64], shl[64];
  int t = threadIdx.x, blk = blockIdx.x;
  int tile = blk & 31, b = blk >> 5;
  const float* xb = x + ((size_t)b << 18) + tile*128;
  for (int v = t; v < 2048; v += 256) {
    int ch = v >> 5, rem = v & 31;
    *(float4*)&xt[ch][rem*4] = *(const float4*)(xb + ch*4096 + rem*4);
  }
  const float* wb = Wt + ((size_t)b << 12);
  for (int v = t; v < 1024; v += 256)
    *(float4*)&wl[v >> 4][(v & 15)*4] = *(const float4*)(wb + v*4);
  if (t < 64) {
    float s1 = 0.f, s2 = 0.f;
    #pragma unroll
    for (int bb = 0; bb < 16; bb++) {
      s1 += statb[bb*128 + t];
      s2 += statb[bb*128 + 64 + t];
    }
    const float inv_cnt = 1.f / 65536.f;           // B*H*W
    float mu  = s1 * inv_cnt;
    float var = s2 * inv_cnt - mu*mu;
    float sc  = gamma[t] * rsqrtf(var + 1e-5f);
    scl[t] = sc;
    shl[t] = beta[t] - sc*mu;
  }
  __syncthreads();

  int pg = t & 15, cg = t >> 4;
  int p0 = pg*4, c0 = cg*4;
  float acc[4][8];
  #pragma unroll
  for (int ci = 0; ci < 4; ci++)
    #pragma unroll
    for (int pj = 0; pj < 8; pj++) acc[ci][pj] = 0.f;
  #pragma unroll 4
  for (int k = 0; k < 64; k++) {
    float4 w4 = *(const float4*)&wl[k][c0];
    float4 xa = *(const float4*)&xt[k][p0];
    float4 xc = *(const float4*)&xt[k][p0 + 64];
    float xs[8] = {xa.x, xa.y, xa.z, xa.w, xc.x, xc.y, xc.z, xc.w};
    float ws[4] = {w4.x, w4.y, w4.z, w4.w};
    #pragma unroll
    for (int ci = 0; ci < 4; ci++)
      #pragma unroll
      for (int pj = 0; pj < 8; pj++) acc[ci][pj] += ws[ci] * xs[pj];
  }
  float4 bias4 = *(const float4*)(biasv + b*64 + c0);
  float bb[4] = {bias4.x, bias4.y, bias4.z, bias4.w};
  float* ob = out + ((size_t)b << 18) + (size_t)tile*128;
  #pragma unroll
  for (int ci = 0; ci < 4; ci++) {
    int c = c0 + ci;
    float sc = scl[c], sh = shl[c];
    float4 xa = *(const float4*)&xt[c][p0];
    float4 xc = *(const float4*)&xt[c][p0 + 64];
    float4 ra, rb;
    ra.x = sc*(acc[ci][0]+bb[ci]) + sh + xa.x;
    ra.y = sc*(acc[ci][1]+bb[ci]) + sh + xa.y;
    ra.z = sc*(acc[ci][2]+bb[ci]) + sh + xa.z;
    ra.w = sc*(acc[ci][3]+bb[ci]) + sh + xa.w;
    rb.x = sc*(acc[ci][4]+bb[ci]) + sh + xc.x;
    rb.y = sc*(acc[ci][5]+bb[ci]) + sh + xc.y;
    rb.z = sc*(acc[ci][6]+bb[ci]) + sh + xc.z;
    rb.w = sc*(acc[ci][7]+bb[ci]) + sh + xc.w;
    *(float4*)(ob + (size_t)c*4096 + p0)      = ra;
    *(float4*)(ob + (size_t)c*4096 + p0 + 64) = rb;
  }
}

extern "C" void kernel_launch(void* const* d_in, const int* in_sizes, int n_in,
                              void* d_out, int out_size, void* d_ws, size_t ws_size,
                              hipStream_t stream)
{
  const float* x    = (const float*)d_in[0];
  const float* w1   = (const float*)d_in[1];
  const float* b1   = (const float*)d_in[2];
  const float* w21  = (const float*)d_in[3];
  const float* b21  = (const float*)d_in[4];
  const float* w22  = (const float*)d_in[5];
  const float* b22  = (const float*)d_in[6];
  const float* w3   = (const float*)d_in[7];
  const float* b3   = (const float*)d_in[8];
  const float* gamma= (const float*)d_in[9];
  const float* beta = (const float*)d_in[10];

  float* ws     = (float*)d_ws;
  float* kvpart = ws;              // 524288 floats
  float* Wt     = ws + 524288;     // 65536
  float* biasv  = ws + 589824;     // 1024
  float* statb  = ws + 590848;     // 2048 (per-batch sums, zeroed by kB)

  hipLaunchKernelGGL(kA, dim3(512), dim3(256), 0, stream, x, w1, b1, w22, b22, kvpart);
  hipLaunchKernelGGL(kB, dim3(16),  dim3(256), 0, stream, kvpart, w3, b3, w21, b21, Wt, biasv, statb);
  hipLaunchKernelGGL(kC, dim3(512), dim3(256), 0, stream, x, Wt, biasv, statb);
  hipLaunchKernelGGL(kD, dim3(512), dim3(256), 0, stream, x, Wt, biasv, statb, gamma, beta,
                     (float*)d_out);
}